// Round 2
// baseline (349.611 us; speedup 1.0000x reference)
//
#include <hip/hip_runtime.h>

#define NL 128          // N_LABELS
#define TT 512          // T
#define NB 512          // B
#define START_IDX 126
#define STOP_IDX 127

typedef __attribute__((ext_vector_type(8))) short bf16x8;
typedef __attribute__((ext_vector_type(4))) float f32x4;
typedef __attribute__((ext_vector_type(4))) unsigned u32x4;

__device__ __forceinline__ short f2bf(float x) {
    union { float f; unsigned u; } v; v.f = x;
    unsigned r = (v.u + 0x7FFFu + ((v.u >> 16) & 1u)) >> 16;  // RNE
    return (short)r;
}

__device__ __forceinline__ unsigned cvt_pk_bf16(float lo, float hi) {
    unsigned r;
    asm("v_cvt_pk_bf16_f32 %0, %1, %2" : "=v"(r) : "v"(lo), "v"(hi));
    return r;   // low half <- lo, high half <- hi
}

// ---------------------------------------------------------------------------
// Pass 1: EL[b][t][p] = exp(logits[b][t][lbl(p)]) with the lane-friendly
// permutation lbl(p) = ((p>>2)&7)*16 + (p>>5)*4 + (p&3). Skips t >= len.
// ---------------------------------------------------------------------------
__global__ __launch_bounds__(256)
void exp_pre(const float* __restrict__ logits, const int* __restrict__ lens,
             float* __restrict__ elp)
{
    const int b = blockIdx.x;
    int len = lens[b]; len = len < 1 ? 1 : (len > TT ? TT : len);
    const float* src = logits + (size_t)b * TT * NL;
    float*       dst = elp    + (size_t)b * TT * NL;
    for (int idx = threadIdx.x; idx < len * 32; idx += 256) {
        const int t = idx >> 5, q = idx & 31;
        const int lbl = (q & 7) * 16 + (q >> 3) * 4;     // 4 consecutive labels
        f32x4 v = *(const f32x4*)(src + t * NL + lbl);
        f32x4 e = { __expf(v[0]), __expf(v[1]), __expf(v[2]), __expf(v[3]) };
        *(f32x4*)(dst + t * NL + q * 4) = e;
    }
}

// ---------------------------------------------------------------------------
// Pass 2: barrier-free batched scan. One wave = 16 batches, full 128 labels.
//   A[R][K] = exp(trans[R][phi(K)]), phi(kk*32+8g+j) = (kk+4*(j>>2))*16+4g+(j&3)
//   B[K][c] = v_c[phi(K)] ; C[R][c] = u_c[R] with R = m*16+4g+reg.
// The phi twist makes C-frag (m,reg) values exactly the lane's next B-frag.
// ---------------------------------------------------------------------------
#define LOADEL(E, T_) do {                                                    \
    const float* _p = elsrc + lbase + (size_t)(T_) * NL;                      \
    _Pragma("unroll")                                                         \
    for (int m_ = 0; m_ < 8; ++m_) {                                          \
        const int off_ = RAW ? (m_ * 16 + 4 * g) : (g * 32 + m_ * 4);         \
        E[m_] = *(const f32x4*)(_p + off_);                                   \
    }                                                                         \
} while (0)

#define STEP(T_, ECUR) do {                                                   \
    f32x4 acc_[8];                                                            \
    _Pragma("unroll") for (int m_ = 0; m_ < 8; ++m_)                          \
        acc_[m_] = (f32x4){0.f, 0.f, 0.f, 0.f};                               \
    _Pragma("unroll") for (int kk_ = 0; kk_ < 4; ++kk_) {                     \
        u32x4 bu_ = { bw[kk_][0], bw[kk_][1], bw[kk_][2], bw[kk_][3] };       \
        bf16x8 bv_ = __builtin_bit_cast(bf16x8, bu_);                         \
        _Pragma("unroll") for (int m_ = 0; m_ < 8; ++m_)                      \
            acc_[m_] = __builtin_amdgcn_mfma_f32_16x16x32_bf16(               \
                afr[m_][kk_], bv_, acc_[m_], 0, 0, 0);                        \
    }                                                                         \
    const bool live_ = (T_) < len;                                            \
    float nv_[8][4];                                                          \
    _Pragma("unroll") for (int m_ = 0; m_ < 8; ++m_)                          \
        _Pragma("unroll") for (int r_ = 0; r_ < 4; ++r_) {                    \
            float el_ = ECUR[m_][r_];                                         \
            if (RAW) el_ = __expf(el_);                                       \
            nv_[m_][r_] = acc_[m_][r_] * el_;                                 \
        }                                                                     \
    { int tl_ = (T_) + 2; if (tl_ > TT - 1) tl_ = TT - 1; LOADEL(ECUR, tl_); }\
    if ((((T_) & 7) == 7)) {                                                  \
        float mx_ = nv_[0][0];                                                \
        _Pragma("unroll") for (int m_ = 0; m_ < 8; ++m_)                      \
            _Pragma("unroll") for (int r_ = 0; r_ < 4; ++r_)                  \
                mx_ = fmaxf(mx_, nv_[m_][r_]);                                \
        mx_ = fmaxf(mx_, __shfl_xor(mx_, 16));                                \
        mx_ = fmaxf(mx_, __shfl_xor(mx_, 32));                                \
        const unsigned eb_ = (__float_as_uint(mx_) >> 23) & 0xFFu;            \
        const float sc_ = __uint_as_float(((253u - eb_) & 0xFFu) << 23);      \
        _Pragma("unroll") for (int m_ = 0; m_ < 8; ++m_)                      \
            _Pragma("unroll") for (int r_ = 0; r_ < 4; ++r_)                  \
                nv_[m_][r_] *= sc_;                                           \
        if (live_) cb += (float)((int)eb_ - 126) * 0.69314718055994531f;      \
    }                                                                         \
    _Pragma("unroll") for (int kk_ = 0; kk_ < 4; ++kk_) {                     \
        const unsigned p0_ = cvt_pk_bf16(nv_[kk_][0],     nv_[kk_][1]);       \
        const unsigned p1_ = cvt_pk_bf16(nv_[kk_][2],     nv_[kk_][3]);       \
        const unsigned p2_ = cvt_pk_bf16(nv_[kk_ + 4][0], nv_[kk_ + 4][1]);   \
        const unsigned p3_ = cvt_pk_bf16(nv_[kk_ + 4][2], nv_[kk_ + 4][3]);   \
        if (live_) {                                                          \
            bw[kk_][0] = p0_; bw[kk_][1] = p1_;                               \
            bw[kk_][2] = p2_; bw[kk_][3] = p3_;                               \
        }                                                                     \
    }                                                                         \
} while (0)

template<bool RAW>
__global__ __launch_bounds__(64)
void crf_scan(const float* __restrict__ logits,
              const int* __restrict__ lens,
              const float* __restrict__ trans,
              const float* __restrict__ elp,
              float* __restrict__ out)
{
    const int b0   = blockIdx.x * 16;
    const int lane = threadIdx.x;
    const int c    = lane & 15;          // batch within group / A row / C col
    const int g    = lane >> 4;          // k-group

    // ---- A fragments: afr[m][kk], lane holds A[m*16+c][kk*32+8g+j] ----
    bf16x8 afr[8][4];
    #pragma unroll
    for (int m = 0; m < 8; ++m) {
        const float* rowp = trans + (m * 16 + c) * NL + 4 * g;
        #pragma unroll
        for (int kk = 0; kk < 4; ++kk) {
            f32x4 lo4 = *(const f32x4*)(rowp + kk * 16);        // phi: j=0..3
            f32x4 hi4 = *(const f32x4*)(rowp + (kk + 4) * 16);  // phi: j=4..7
            bf16x8 a;
            #pragma unroll
            for (int j = 0; j < 4; ++j) {
                a[j]     = f2bf(__expf(lo4[j]));
                a[j + 4] = f2bf(__expf(hi4[j]));
            }
            afr[m][kk] = a;
        }
    }

    int len = lens[b0 + c]; len = len < 1 ? 1 : (len > TT ? TT : len);
    int glen = len;
    #pragma unroll
    for (int d = 1; d < 16; d <<= 1) {
        int o = __shfl_xor(glen, d);
        glen = glen > o ? glen : o;
    }

    // ---- B registers: packed bf16 pairs; one-hot at START (=label 126) ----
    // phi^-1(126): m=7,g=3,reg=2 -> kk=3, j=6 -> word 3, low half, g==3 lanes.
    unsigned bw[4][4];
    #pragma unroll
    for (int kk = 0; kk < 4; ++kk)
        #pragma unroll
        for (int i = 0; i < 4; ++i) bw[kk][i] = 0u;
    if (g == 3) bw[3][3] = 0x00003F80u;

    float cb = 0.f;                      // per-batch log-scale accumulator
    const size_t lbase = (size_t)(b0 + c) * TT * NL;
    const float* elsrc = RAW ? logits : elp;

    f32x4 e0[8], e1[8];
    LOADEL(e0, 0);
    LOADEL(e1, 1);

    for (int t = 0; t < glen; t += 2) {
        STEP(t,     e0);
        STEP(t + 1, e1);
    }

    // ---- out[b] = cb + log( sum_L v[L] * exp(trans[STOP][L]) ) ----
    float s = 0.f;
    const float* stopr = trans + STOP_IDX * NL + 4 * g;
    #pragma unroll
    for (int kk = 0; kk < 4; ++kk) {
        f32x4 t0 = *(const f32x4*)(stopr + kk * 16);
        f32x4 t1 = *(const f32x4*)(stopr + (kk + 4) * 16);
        #pragma unroll
        for (int i = 0; i < 2; ++i) {
            const unsigned w = bw[kk][i];
            s += __uint_as_float(w << 16)          * __expf(t0[2 * i]);
            s += __uint_as_float(w & 0xFFFF0000u)  * __expf(t0[2 * i + 1]);
        }
        #pragma unroll
        for (int i = 2; i < 4; ++i) {
            const unsigned w = bw[kk][i];
            s += __uint_as_float(w << 16)          * __expf(t1[2 * (i - 2)]);
            s += __uint_as_float(w & 0xFFFF0000u)  * __expf(t1[2 * (i - 2) + 1]);
        }
    }
    s += __shfl_xor(s, 16);
    s += __shfl_xor(s, 32);
    if (lane < 16) out[b0 + c] = cb + __logf(s);
}

extern "C" void kernel_launch(void* const* d_in, const int* in_sizes, int n_in,
                              void* d_out, int out_size, void* d_ws, size_t ws_size,
                              hipStream_t stream) {
    const float* logits = (const float*)d_in[0];
    const int*   lens   = (const int*)d_in[1];
    const float* trans  = (const float*)d_in[2];
    float*       outp   = (float*)d_out;

    const size_t need = (size_t)NB * TT * NL * sizeof(float);
    if (ws_size >= need) {
        float* elp = (float*)d_ws;
        exp_pre<<<NB, 256, 0, stream>>>(logits, lens, elp);
        crf_scan<false><<<NB / 16, 64, 0, stream>>>(logits, lens, trans, elp, outp);
    } else {
        crf_scan<true><<<NB / 16, 64, 0, stream>>>(logits, lens, trans, nullptr, outp);
    }
}

// Round 3
// 263.838 us; speedup vs baseline: 1.3251x; 1.3251x over previous
//
#include <hip/hip_runtime.h>

#define NL 128          // N_LABELS
#define TT 512          // T
#define NB 512          // B
#define START_IDX 126
#define STOP_IDX 127

typedef __attribute__((ext_vector_type(8))) short bf16x8;
typedef __attribute__((ext_vector_type(4))) float f32x4;
typedef __attribute__((ext_vector_type(4))) unsigned u32x4;

__device__ __forceinline__ short f2bf(float x) {
    union { float f; unsigned u; } v; v.f = x;
    unsigned r = (v.u + 0x7FFFu + ((v.u >> 16) & 1u)) >> 16;  // RNE
    return (short)r;
}

__device__ __forceinline__ unsigned cvt_pk_bf16(float lo, float hi) {
    unsigned r;
    asm("v_cvt_pk_bf16_f32 %0, %1, %2" : "=v"(r) : "v"(lo), "v"(hi));
    return r;   // low half <- lo, high half <- hi
}

// ---------------------------------------------------------------------------
// Pass 1: EL[b][t][q*4+j] = exp(logits[b][t][lbl(q,j)]) with the lane-friendly
// permutation lbl(q,j) = (q&7)*16 + (q>>3)*4 + j. Skips t >= len.
// ---------------------------------------------------------------------------
__global__ __launch_bounds__(256)
void exp_pre(const float* __restrict__ logits, const int* __restrict__ lens,
             float* __restrict__ elp)
{
    const int b = blockIdx.x;
    int len = lens[b]; len = len < 1 ? 1 : (len > TT ? TT : len);
    const float* src = logits + (size_t)b * TT * NL;
    float*       dst = elp    + (size_t)b * TT * NL;
    for (int idx = threadIdx.x; idx < len * 32; idx += 256) {
        const int t = idx >> 5, q = idx & 31;
        const int lbl = (q & 7) * 16 + (q >> 3) * 4;     // 4 consecutive labels
        f32x4 v = *(const f32x4*)(src + t * NL + lbl);
        f32x4 e = { __expf(v[0]), __expf(v[1]), __expf(v[2]), __expf(v[3]) };
        *(f32x4*)(dst + t * NL + q * 4) = e;
    }
}

// ---------------------------------------------------------------------------
// Pass 2: one wave per batch, batch replicated across all 16 MFMA columns.
//   A[R][K] = exp(trans[R][phi(K)]), phi(kk*32+8g+j) = (kk+4*(j>>2))*16+4g+(j&3)
//   B[K][c] = v[phi(K)] (same for every col c) ; C[R][c] = u[R], R=16m+4g+reg.
// The phi twist makes C-frag (m,reg) values exactly the lane's next B-frag:
// no cross-lane traffic, no LDS, no barriers. len is wave-uniform -> loop
// runs exactly len steps, no freeze masks.
// ---------------------------------------------------------------------------
#define LOADEL(E, T_) do {                                                    \
    const float* _p = elsrc + lbase + (size_t)(T_) * NL;                      \
    _Pragma("unroll")                                                         \
    for (int m_ = 0; m_ < 8; ++m_) {                                          \
        const int off_ = RAW ? (m_ * 16 + 4 * g) : (g * 32 + m_ * 4);         \
        E[m_] = *(const f32x4*)(_p + off_);                                   \
    }                                                                         \
} while (0)

#define STEP(T_, ECUR, RS_) do {                                              \
    f32x4 acc_[8];                                                            \
    _Pragma("unroll") for (int m_ = 0; m_ < 8; ++m_)                          \
        acc_[m_] = (f32x4){0.f, 0.f, 0.f, 0.f};                               \
    _Pragma("unroll") for (int kk_ = 0; kk_ < 4; ++kk_) {                     \
        u32x4 bu_ = { bw[kk_][0], bw[kk_][1], bw[kk_][2], bw[kk_][3] };       \
        bf16x8 bv_ = __builtin_bit_cast(bf16x8, bu_);                         \
        _Pragma("unroll") for (int m_ = 0; m_ < 8; ++m_)                      \
            acc_[m_] = __builtin_amdgcn_mfma_f32_16x16x32_bf16(               \
                afr[m_][kk_], bv_, acc_[m_], 0, 0, 0);                        \
    }                                                                         \
    float nv_[8][4];                                                          \
    _Pragma("unroll") for (int m_ = 0; m_ < 8; ++m_)                          \
        _Pragma("unroll") for (int r_ = 0; r_ < 4; ++r_) {                    \
            float el_ = ECUR[m_][r_];                                         \
            if (RAW) el_ = __expf(el_);                                       \
            nv_[m_][r_] = acc_[m_][r_] * el_;                                 \
        }                                                                     \
    { int tp_ = (T_) + 2; if (tp_ > TT - 1) tp_ = TT - 1; LOADEL(ECUR, tp_); }\
    if (RS_) {                                                                \
        float mx_ = nv_[0][0];                                                \
        _Pragma("unroll") for (int m_ = 0; m_ < 8; ++m_)                      \
            _Pragma("unroll") for (int r_ = 0; r_ < 4; ++r_)                  \
                mx_ = fmaxf(mx_, nv_[m_][r_]);                                \
        mx_ = fmaxf(mx_, __shfl_xor(mx_, 16));                                \
        mx_ = fmaxf(mx_, __shfl_xor(mx_, 32));                                \
        const unsigned eb_ = (__float_as_uint(mx_) >> 23) & 0xFFu;            \
        const float sc_ = __uint_as_float(((253u - eb_) & 0xFFu) << 23);      \
        _Pragma("unroll") for (int m_ = 0; m_ < 8; ++m_)                      \
            _Pragma("unroll") for (int r_ = 0; r_ < 4; ++r_)                  \
                nv_[m_][r_] *= sc_;                                           \
        cbi += (int)eb_ - 126;                                                \
    }                                                                         \
    _Pragma("unroll") for (int kk_ = 0; kk_ < 4; ++kk_) {                     \
        bw[kk_][0] = cvt_pk_bf16(nv_[kk_][0],     nv_[kk_][1]);               \
        bw[kk_][1] = cvt_pk_bf16(nv_[kk_][2],     nv_[kk_][3]);               \
        bw[kk_][2] = cvt_pk_bf16(nv_[kk_ + 4][0], nv_[kk_ + 4][1]);           \
        bw[kk_][3] = cvt_pk_bf16(nv_[kk_ + 4][2], nv_[kk_ + 4][3]);           \
    }                                                                         \
} while (0)

template<bool RAW>
__global__ __launch_bounds__(64, 1)
void crf_scan(const float* __restrict__ logits,
              const int* __restrict__ lens,
              const float* __restrict__ trans,
              const float* __restrict__ elp,
              float* __restrict__ out)
{
    const int b    = blockIdx.x;
    const int lane = threadIdx.x;
    const int c    = lane & 15;          // A row within m-tile / replicated col
    const int g    = lane >> 4;          // k-group

    // ---- A fragments: afr[m][kk], lane holds A[m*16+c][kk*32+8g+j] ----
    bf16x8 afr[8][4];
    #pragma unroll
    for (int m = 0; m < 8; ++m) {
        const float* rowp = trans + (m * 16 + c) * NL + 4 * g;
        #pragma unroll
        for (int kk = 0; kk < 4; ++kk) {
            f32x4 lo4 = *(const f32x4*)(rowp + kk * 16);        // phi: j=0..3
            f32x4 hi4 = *(const f32x4*)(rowp + (kk + 4) * 16);  // phi: j=4..7
            bf16x8 a;
            #pragma unroll
            for (int j = 0; j < 4; ++j) {
                a[j]     = f2bf(__expf(lo4[j]));
                a[j + 4] = f2bf(__expf(hi4[j]));
            }
            afr[m][kk] = a;
        }
    }

    int len0 = lens[b]; len0 = len0 < 1 ? 1 : (len0 > TT ? TT : len0);
    const int len = __builtin_amdgcn_readfirstlane(len0);

    // ---- B registers: packed bf16 pairs; one-hot at START (=label 126) ----
    // phi^-1(126): kk=3, j=6 on g==3 lanes -> word 3, low half.
    unsigned bw[4][4];
    #pragma unroll
    for (int kk = 0; kk < 4; ++kk)
        #pragma unroll
        for (int i = 0; i < 4; ++i) bw[kk][i] = 0u;
    if (g == 3) bw[3][3] = 0x00003F80u;

    int cbi = 0;                         // rescale exponent count (exact)
    const size_t lbase = (size_t)b * TT * NL;
    const float* elsrc = RAW ? logits : elp;

    f32x4 e0[8], e1[8];
    LOADEL(e0, 0);
    LOADEL(e1, 1);

    int t = 0;
    const int tmain = len & ~7;
    for (; t < tmain; t += 8) {
        STEP(t + 0, e0, 0);
        STEP(t + 1, e1, 0);
        STEP(t + 2, e0, 0);
        STEP(t + 3, e1, 0);
        STEP(t + 4, e0, 0);
        STEP(t + 5, e1, 0);
        STEP(t + 6, e0, 0);
        STEP(t + 7, e1, 1);              // rescale every 8 steps
    }
    // tail (<8 steps, no rescale needed: growth < e^60 stays in fp32/bf16)
    if (t < len) { STEP(t, e0, 0); ++t; }
    if (t < len) { STEP(t, e1, 0); ++t; }
    if (t < len) { STEP(t, e0, 0); ++t; }
    if (t < len) { STEP(t, e1, 0); ++t; }
    if (t < len) { STEP(t, e0, 0); ++t; }
    if (t < len) { STEP(t, e1, 0); ++t; }
    if (t < len) { STEP(t, e0, 0); ++t; }

    // ---- out[b] = cb + log( sum_L v[L] * exp(trans[STOP][L]) ) ----
    float s = 0.f;
    const float* stopr = trans + STOP_IDX * NL + 4 * g;
    #pragma unroll
    for (int kk = 0; kk < 4; ++kk) {
        f32x4 t0 = *(const f32x4*)(stopr + kk * 16);
        f32x4 t1 = *(const f32x4*)(stopr + (kk + 4) * 16);
        #pragma unroll
        for (int i = 0; i < 2; ++i) {
            const unsigned w = bw[kk][i];
            s += __uint_as_float(w << 16)          * __expf(t0[2 * i]);
            s += __uint_as_float(w & 0xFFFF0000u)  * __expf(t0[2 * i + 1]);
        }
        #pragma unroll
        for (int i = 2; i < 4; ++i) {
            const unsigned w = bw[kk][i];
            s += __uint_as_float(w << 16)          * __expf(t1[2 * (i - 2)]);
            s += __uint_as_float(w & 0xFFFF0000u)  * __expf(t1[2 * (i - 2) + 1]);
        }
    }
    s += __shfl_xor(s, 16);
    s += __shfl_xor(s, 32);
    if (lane == 0)
        out[b] = (float)cbi * 0.69314718055994531f + __logf(s);
}

extern "C" void kernel_launch(void* const* d_in, const int* in_sizes, int n_in,
                              void* d_out, int out_size, void* d_ws, size_t ws_size,
                              hipStream_t stream) {
    const float* logits = (const float*)d_in[0];
    const int*   lens   = (const int*)d_in[1];
    const float* trans  = (const float*)d_in[2];
    float*       outp   = (float*)d_out;

    const size_t need = (size_t)NB * TT * NL * sizeof(float);
    if (ws_size >= need) {
        float* elp = (float*)d_ws;
        exp_pre<<<NB, 256, 0, stream>>>(logits, lens, elp);
        crf_scan<false><<<NB, 64, 0, stream>>>(logits, lens, trans, elp, outp);
    } else {
        crf_scan<true><<<NB, 64, 0, stream>>>(logits, lens, trans, nullptr, outp);
    }
}

// Round 4
// 252.637 us; speedup vs baseline: 1.3838x; 1.0443x over previous
//
#include <hip/hip_runtime.h>

#define NL 128          // N_LABELS
#define TT 512          // T
#define NB 512          // B
#define START_IDX 126
#define STOP_IDX 127

typedef __attribute__((ext_vector_type(8))) short bf16x8;
typedef __attribute__((ext_vector_type(4))) float f32x4;

__device__ __forceinline__ short f2bf(float x) {
    union { float f; unsigned u; } v; v.f = x;
    unsigned r = (v.u + 0x7FFFu + ((v.u >> 16) & 1u)) >> 16;  // RNE
    return (short)r;
}

__device__ __forceinline__ unsigned cvt_pk_bf16(float lo, float hi) {
    unsigned r;
    asm("v_cvt_pk_bf16_f32 %0, %1, %2" : "=v"(r) : "v"(lo), "v"(hi));
    return r;   // low half <- lo, high half <- hi
}

// ---------------------------------------------------------------------------
// Pass 1: EL[b][t][q*4+j] = exp(logits[b][t][lbl(q,j)]), lbl = (q&7)*16+(q>>3)*4+j.
// ---------------------------------------------------------------------------
__global__ __launch_bounds__(256)
void exp_pre(const float* __restrict__ logits, const int* __restrict__ lens,
             float* __restrict__ elp)
{
    const int b = blockIdx.x;
    int len = lens[b]; len = len < 1 ? 1 : (len > TT ? TT : len);
    const float* src = logits + (size_t)b * TT * NL;
    float*       dst = elp    + (size_t)b * TT * NL;
    for (int idx = threadIdx.x; idx < len * 32; idx += 256) {
        const int t = idx >> 5, q = idx & 31;
        const int lbl = (q & 7) * 16 + (q >> 3) * 4;
        f32x4 v = *(const f32x4*)(src + t * NL + lbl);
        f32x4 e = { __expf(v[0]), __expf(v[1]), __expf(v[2]), __expf(v[3]) };
        *(f32x4*)(dst + t * NL + q * 4) = e;
    }
}

// ---------------------------------------------------------------------------
// Pass 2: 16 batches per block (MFMA columns), 4 waves x 2 M-tiles (rows).
// v exchanged per step through a double-buffered LDS (8B chunks per (c,g),
// chunk index XOR'd with c&3; the XOR is compensated in the A-fragments).
// Lag-1 cross-wave max (smax) drives exact power-of-2 rescaling every 4 steps.
// ---------------------------------------------------------------------------
#define LOADEL(E, T_) do {                                                    \
    _Pragma("unroll")                                                         \
    for (int m_ = 0; m_ < 2; ++m_) {                                          \
        const int off_ = RAW ? ((2*w + m_)*16 + 4*g) : (g*32 + (2*w + m_)*4); \
        E[m_] = *(const f32x4*)(elsrc + (size_t)(T_) * NL + off_);            \
    }                                                                         \
} while (0)

#define STEP(T_, ECUR, RBUF, WBUF) do {                                       \
    bf16x8 bwv_[4];                                                           \
    _Pragma("unroll")                                                         \
    for (int kkp_ = 0; kkp_ < 4; ++kkp_)                                      \
        bwv_[kkp_] = *(const bf16x8*)((RBUF) + kkp_ * 8);                     \
    f32x4 acc0_ = {0.f,0.f,0.f,0.f}, acc1_ = {0.f,0.f,0.f,0.f};               \
    _Pragma("unroll")                                                         \
    for (int kkp_ = 0; kkp_ < 4; ++kkp_) {                                    \
        acc0_ = __builtin_amdgcn_mfma_f32_16x16x32_bf16(afr[0][kkp_], bwv_[kkp_], acc0_, 0,0,0); \
        acc1_ = __builtin_amdgcn_mfma_f32_16x16x32_bf16(afr[1][kkp_], bwv_[kkp_], acc1_, 0,0,0); \
    }                                                                         \
    float nv_[2][4];                                                          \
    _Pragma("unroll")                                                         \
    for (int r_ = 0; r_ < 4; ++r_) {                                          \
        float e0_ = ECUR[0][r_], e1_ = ECUR[1][r_];                           \
        if (RAW) { e0_ = __expf(e0_); e1_ = __expf(e1_); }                    \
        nv_[0][r_] = acc0_[r_] * e0_;                                         \
        nv_[1][r_] = acc1_[r_] * e1_;                                         \
    }                                                                         \
    { int tp_ = (T_) + 2; if (tp_ > glen - 1) tp_ = glen - 1; LOADEL(ECUR, tp_); } \
    if (((T_) & 3) == 0 && (T_) > 0) {      /* consume lag-1 max */           \
        float mx_ = fmaxf(fmaxf(smax[0][c], smax[1][c]),                      \
                          fmaxf(smax[2][c], smax[3][c]));                     \
        const unsigned eb_ = (__float_as_uint(mx_) >> 23) & 0xFFu;            \
        const float sc_ = __uint_as_float(((253u - eb_) & 0xFFu) << 23);      \
        _Pragma("unroll")                                                     \
        for (int m_ = 0; m_ < 2; ++m_)                                        \
            _Pragma("unroll")                                                 \
            for (int r_ = 0; r_ < 4; ++r_) nv_[m_][r_] *= sc_;                \
        if ((T_) < lenc) cbi += (int)eb_ - 126;                               \
    }                                                                         \
    if (((T_) & 3) == 3) {                  /* publish per-wave max */        \
        float lm_ = nv_[0][0];                                                \
        _Pragma("unroll")                                                     \
        for (int m_ = 0; m_ < 2; ++m_)                                        \
            _Pragma("unroll")                                                 \
            for (int r_ = 0; r_ < 4; ++r_) lm_ = fmaxf(lm_, nv_[m_][r_]);     \
        lm_ = fmaxf(lm_, __shfl_xor(lm_, 16));                                \
        lm_ = fmaxf(lm_, __shfl_xor(lm_, 32));                                \
        if (g == 0) smax[w][c] = lm_;                                         \
    }                                                                         \
    if ((T_) < lenc) {                      /* predicated v' publish */       \
        _Pragma("unroll")                                                     \
        for (int m_ = 0; m_ < 2; ++m_) {                                      \
            const unsigned w0_ = cvt_pk_bf16(nv_[m_][0], nv_[m_][1]);         \
            const unsigned w1_ = cvt_pk_bf16(nv_[m_][2], nv_[m_][3]);         \
            const int M_ = 2*w + m_;                                          \
            const int p_ = (((M_ & 3) ^ cx) << 1) + (M_ >> 2);                \
            *(unsigned long long*)((WBUF) + p_ * 4) =                         \
                (unsigned long long)w0_ | ((unsigned long long)w1_ << 32);    \
        }                                                                     \
    }                                                                         \
    __syncthreads();                                                          \
} while (0)

template<bool RAW>
__global__ __launch_bounds__(256, 1)
void crf_scan(const float* __restrict__ logits,
              const int* __restrict__ lens,
              const float* __restrict__ trans,
              const float* __restrict__ elp,
              float* __restrict__ out)
{
    const int b0   = blockIdx.x * 16;
    const int tid  = threadIdx.x;
    const int w    = tid >> 6;           // wave: owns M-tiles {2w, 2w+1}
    const int lane = tid & 63;
    const int c    = lane & 15;          // batch within group / A row / C col
    const int g    = lane >> 4;          // k-group
    const int cx   = c & 3;              // chunk XOR key

    __shared__ __align__(16) short vbuf[2][16 * 4 * 32];  // [(c*4+g)*32 + p*4 + r]
    __shared__ float smax[4][16];

    // ---- A fragments, XOR-compensated: afr[m][kkp] holds logical kk = kkp^cx
    bf16x8 afr[2][4];
    #pragma unroll
    for (int m = 0; m < 2; ++m) {
        const int M = 2*w + m;
        const float* rowp = trans + (M*16 + c) * NL + 4*g;
        #pragma unroll
        for (int kkp = 0; kkp < 4; ++kkp) {
            const int kk = kkp ^ cx;
            f32x4 lo4 = *(const f32x4*)(rowp + kk * 16);
            f32x4 hi4 = *(const f32x4*)(rowp + (kk + 4) * 16);
            bf16x8 a;
            #pragma unroll
            for (int j = 0; j < 4; ++j) {
                a[j]     = f2bf(__expf(lo4[j]));
                a[j + 4] = f2bf(__expf(hi4[j]));
            }
            afr[m][kkp] = a;
        }
    }

    int lenc = lens[b0 + c];
    lenc = lenc < 1 ? 1 : (lenc > TT ? TT : lenc);
    int gl = lenc;
    #pragma unroll
    for (int d = 1; d < 16; d <<= 1) { int o = __shfl_xor(gl, d); gl = gl > o ? gl : o; }
    const int glen = __builtin_amdgcn_readfirstlane(gl);

    short* vb0 = &vbuf[0][(c*4 + g) * 32];
    short* vb1 = &vbuf[1][(c*4 + g) * 32];

    // init buf0: zeros + one-hot at START (label 126: M=7, g=3, r=2)
    if (w == 0) {
        #pragma unroll
        for (int q = 0; q < 4; ++q) *(f32x4*)(vb0 + q * 8) = (f32x4){0.f,0.f,0.f,0.f};
        if (g == 3) vb0[(((3 ^ cx) << 1) + 1) * 4 + 2] = (short)0x3F80;
    }

    int cbi = 0;
    const float* elsrc = (RAW ? logits : elp) + (size_t)(b0 + c) * TT * NL;
    f32x4 e0[2], e1[2];
    LOADEL(e0, 0);
    LOADEL(e1, 1);

    __syncthreads();

    for (int t = 0; t < glen; t += 2) {
        STEP(t, e0, vb0, vb1);
        if (t + 1 < glen) STEP(t + 1, e1, vb1, vb0);
    }

    // ---- epilogue: out[b] = cb*ln2 + log( sum_L v[L] * exp(trans[STOP][L]) )
    if (w == 0) {
        const short* vf = (glen & 1) ? vb1 : vb0;
        float s = 0.f;
        #pragma unroll
        for (int p = 0; p < 8; ++p) {
            const int M = ((p >> 1) ^ cx) + 4 * (p & 1);
            const float* tp = trans + STOP_IDX * NL + M * 16 + 4 * g;
            #pragma unroll
            for (int r = 0; r < 4; ++r) {
                const float vv = __uint_as_float(((unsigned)(unsigned short)vf[p * 4 + r]) << 16);
                s += vv * __expf(tp[r]);
            }
        }
        s += __shfl_xor(s, 16);
        s += __shfl_xor(s, 32);
        if (g == 0)
            out[b0 + c] = (float)cbi * 0.69314718055994531f + __logf(s);
    }
}

extern "C" void kernel_launch(void* const* d_in, const int* in_sizes, int n_in,
                              void* d_out, int out_size, void* d_ws, size_t ws_size,
                              hipStream_t stream) {
    const float* logits = (const float*)d_in[0];
    const int*   lens   = (const int*)d_in[1];
    const float* trans  = (const float*)d_in[2];
    float*       outp   = (float*)d_out;

    const size_t need = (size_t)NB * TT * NL * sizeof(float);
    if (ws_size >= need) {
        float* elp = (float*)d_ws;
        exp_pre<<<NB, 256, 0, stream>>>(logits, lens, elp);
        crf_scan<false><<<NB / 16, 256, 0, stream>>>(logits, lens, trans, elp, outp);
    } else {
        crf_scan<true><<<NB / 16, 256, 0, stream>>>(logits, lens, trans, nullptr, outp);
    }
}